// Round 10
// baseline (102.107 us; speedup 1.0000x reference)
//
#include <hip/hip_runtime.h>

#define BB 2
#define LL 1024
#define DD 1024
#define HH 16
#define NC 16
#define EPSF 1e-8f

typedef __attribute__((ext_vector_type(8))) short bf16x8;
typedef __attribute__((ext_vector_type(4))) float f32x4;
typedef unsigned short u16;

static __device__ inline u16 f2bf(float f) {
    unsigned int u = __builtin_bit_cast(unsigned int, f);
    u += 0x7fff + ((u >> 16) & 1);     // RNE
    return (u16)(u >> 16);
}
static __device__ inline float bf2f(u16 v) {
    unsigned int u = ((unsigned int)v) << 16;
    return __builtin_bit_cast(float, u);
}
static __device__ inline void gload_lds16(const u16* g, u16* l) {
    __builtin_amdgcn_global_load_lds((const __attribute__((address_space(1))) void*)g,
                                     (__attribute__((address_space(3))) void*)l, 16, 0, 0);
}

// ---------------- fp32 -> bf16 convert: X (2M), Wq (1M), Wv (1M)
__global__ __launch_bounds__(256) void cvt_k(const float* __restrict__ X,
                                             const float* __restrict__ Wq,
                                             const float* __restrict__ Wv,
                                             u16* __restrict__ Xb,
                                             u16* __restrict__ Wqb,
                                             u16* __restrict__ Wvb)
{
    int i = (blockIdx.x * 256 + threadIdx.x) * 4;
    const float* s; u16* d; int off;
    if (i < 2*1024*1024)      { s = X;  d = Xb;  off = i; }
    else if (i < 3*1024*1024) { s = Wq; d = Wqb; off = i - 2*1024*1024; }
    else                      { s = Wv; d = Wvb; off = i - 3*1024*1024; }
    float4 v = *(const float4*)(s + off);
    ushort4 o;
    o.x = f2bf(v.x); o.y = f2bf(v.y); o.z = f2bf(v.z); o.w = f2bf(v.w);
    *(ushort4*)(d + off) = o;
}

// ---------------- bf16 MFMA GEMM + fused per-head RMSNorm, bf16 out.
// 128(M) x 64(N) tile, BK=64 via two ping LDS slices; 512 blocks (2/CU).
// z=1 (V) blocks additionally compute the two per-chunk S tiles
// S_c^T = V_c^T K_c for their 2 chunks (V from registers, K from Xb via L2),
// writing bf16 flat MFMA C-layout — replaces the kv_chunk kernel bit-exactly.
__global__ __launch_bounds__(256) void gemm_fused(const u16* __restrict__ Xb,
                                                  const u16* __restrict__ Wqb,
                                                  const u16* __restrict__ Wvb,
                                                  const float* __restrict__ qw,
                                                  const float* __restrict__ vw,
                                                  u16* __restrict__ Qb,
                                                  u16* __restrict__ Vb,
                                                  u16* __restrict__ S)
{
    const int K = DD, N = DD;
    const u16* W = blockIdx.z ? Wvb : Wqb;
    const float* nw = blockIdx.z ? vw : qw;
    u16* Y = blockIdx.z ? Vb : Qb;
    __shared__ u16 arena[18432];   // 36 KB: As0|As1|Bs0|Bs1 (24KB) -> Kt0|Kt1|Vt0|Vt1
    u16* As0 = arena;            // 4096
    u16* As1 = arena + 4096;
    u16* Bs0 = arena + 8192;     // 2048
    u16* Bs1 = arena + 10240;
    typedef u16 (*tile_t)[72];
    tile_t Kt0 = (tile_t)(arena);           // [d][l] chunk 0
    tile_t Kt1 = (tile_t)(arena + 4608);
    tile_t Vt0 = (tile_t)(arena + 9216);    // [e][l] chunk 0
    tile_t Vt1 = (tile_t)(arena + 13824);

    const int tid = threadIdx.x, w = tid >> 6, lane = tid & 63;
    const int quad = lane >> 4, l16 = lane & 15;
    const int m0 = blockIdx.y * 128, n0 = blockIdx.x * 64;
    const int lrow = lane >> 2, lcol = (lane & 3) * 8;

    const u16* gA0 = Xb + (size_t)(m0 + w*16 + lrow) * K + lcol;
    const u16* gA1 = gA0 + (size_t)64 * K;
    const u16* gB0 = W + (size_t)(n0 + w*16 + lrow) * K + lcol;
    u16* lA0_0 = &As0[(w*16) * 32];      u16* lA0_1 = &As1[(w*16) * 32];
    u16* lA1_0 = &As0[(64 + w*16) * 32]; u16* lA1_1 = &As1[(64 + w*16) * 32];
    u16* lB0_0 = &Bs0[(w*16) * 32];      u16* lB0_1 = &Bs1[(w*16) * 32];

    f32x4 acc[2][4] = {};
    for (int k0 = 0; k0 < K; k0 += 64) {
        gload_lds16(gA0 + k0,      lA0_0);
        gload_lds16(gA0 + k0 + 32, lA0_1);
        gload_lds16(gA1 + k0,      lA1_0);
        gload_lds16(gA1 + k0 + 32, lA1_1);
        gload_lds16(gB0 + k0,      lB0_0);
        gload_lds16(gB0 + k0 + 32, lB0_1);
        __syncthreads();
        #pragma unroll
        for (int hh = 0; hh < 2; ++hh) {
            const u16* Ah = hh ? As1 : As0;
            const u16* Bh = hh ? Bs1 : Bs0;
            bf16x8 af[2], bfr[4];
            #pragma unroll
            for (int i = 0; i < 2; ++i)
                af[i] = *(const bf16x8*)&Ah[(w*32 + i*16 + l16) * 32 + quad*8];
            #pragma unroll
            for (int j = 0; j < 4; ++j)
                bfr[j] = *(const bf16x8*)&Bh[(j*16 + l16) * 32 + quad*8];
            #pragma unroll
            for (int i = 0; i < 2; ++i)
                #pragma unroll
                for (int j = 0; j < 4; ++j)
                    acc[i][j] = __builtin_amdgcn_mfma_f32_16x16x32_bf16(af[i], bfr[j], acc[i][j], 0, 0, 0);
        }
        __syncthreads();
    }
    // NOTE: after the final barrier no one reads As/Bs again -> arena reusable.

    float wv4[4];
    #pragma unroll
    for (int j = 0; j < 4; ++j) wv4[j] = nw[n0 + j*16 + l16];
    #pragma unroll
    for (int i = 0; i < 2; ++i) {
        float ss[4];
        #pragma unroll
        for (int r = 0; r < 4; ++r) {
            float s = 0.f;
            #pragma unroll
            for (int j = 0; j < 4; ++j) s += acc[i][j][r] * acc[i][j][r];
            ss[r] = s;
        }
        #pragma unroll
        for (int off = 1; off < 16; off <<= 1)
            #pragma unroll
            for (int r = 0; r < 4; ++r) ss[r] += __shfl_xor(ss[r], off, 64);
        float sc[4];
        #pragma unroll
        for (int r = 0; r < 4; ++r) sc[r] = rsqrtf(ss[r] * (1.f/64.f) + EPSF);
        #pragma unroll
        for (int r = 0; r < 4; ++r) {
            const int lr = w*32 + i*16 + quad*4 + r;    // local row in 128-tile
            u16* yp = Y + (size_t)(m0 + lr) * N + n0;
            tile_t Vt = (lr & 64) ? Vt1 : Vt0;
            #pragma unroll
            for (int j = 0; j < 4; ++j) {
                u16 o = f2bf(acc[i][j][r] * sc[r] * wv4[j]);
                yp[j*16 + l16] = o;
                if (blockIdx.z) Vt[j*16 + l16][lr & 63] = o;   // V^T into LDS
            }
        }
    }

    if (blockIdx.z == 0) return;

    // stage K^T for both chunks: two passes of 64 rows, 16B coalesced loads
    {
        const int row = tid >> 2, q = tid & 3;
        #pragma unroll
        for (int p = 0; p < 2; ++p) {
            const u16* gk = Xb + (size_t)(m0 + p*64 + row) * DD + n0 + q*16;
            u16 kk[16];
            #pragma unroll
            for (int i = 0; i < 16; i += 4)
                *(ushort4*)&kk[i] = *(const ushort4*)(gk + i);
            tile_t Kt = p ? Kt1 : Kt0;
            #pragma unroll
            for (int i = 0; i < 16; ++i)
                Kt[q*16 + i][row] = kk[i];
        }
    }
    __syncthreads();

    // S_c^T = V_c^T K_c, each wave one 32x32 quadrant per chunk (same tiling
    // as the old kv_chunk kernel -> bit-identical S values and layout)
    const int b = m0 >> 10, h = blockIdx.x;
    const int c0 = (m0 & 1023) >> 6;
    const int bh = b*16 + h;
    const int me = (w & 1) * 32, nd = (w >> 1) * 32;
    #pragma unroll
    for (int cc = 0; cc < 2; ++cc) {
        tile_t Kt = cc ? Kt1 : Kt0;
        tile_t Vt = cc ? Vt1 : Vt0;
        f32x4 sacc[2][2] = {};
        #pragma unroll
        for (int k0 = 0; k0 < 64; k0 += 32) {
            bf16x8 av[2], bv[2];
            #pragma unroll
            for (int i = 0; i < 2; ++i)
                av[i] = *(const bf16x8*)&Vt[me + i*16 + l16][k0 + quad*8];
            #pragma unroll
            for (int j = 0; j < 2; ++j)
                bv[j] = *(const bf16x8*)&Kt[nd + j*16 + l16][k0 + quad*8];
            #pragma unroll
            for (int i = 0; i < 2; ++i)
                #pragma unroll
                for (int j = 0; j < 2; ++j)
                    sacc[i][j] = __builtin_amdgcn_mfma_f32_16x16x32_bf16(av[i], bv[j], sacc[i][j], 0, 0, 0);
        }
        u16* Sp = S + ((size_t)(bh*NC + c0 + cc) << 12) + w*1024;
        #pragma unroll
        for (int i = 0; i < 2; ++i)
            #pragma unroll
            for (int j = 0; j < 2; ++j)
                #pragma unroll
                for (int r = 0; r < 4; ++r)
                    Sp[(i*2 + j)*256 + r*64 + lane] = f2bf(sacc[i][j][r]);
    }
}

// ---------------- out = tril(Q K^T) @ V + Q @ S0; block sums its own prefix
// from the parallel per-chunk S tiles (L2-resident, avg 7.5 x 8 KB).
__global__ __launch_bounds__(256) void out_k2(const u16* __restrict__ Xb,
                                              const u16* __restrict__ Qb,
                                              const u16* __restrict__ Vb,
                                              const u16* __restrict__ S,
                                              float* __restrict__ out)
{
    const int c = 15 - (blockIdx.x & 15);   // heavy (large-c) blocks first
    const int bh = blockIdx.x >> 4;
    const int h = bh & 15, b = bh >> 4;
    __shared__ u16 Qs[64][72];   // [l][d]
    __shared__ u16 Ks[64][72];   // [l'][d] -> later Ps [l][l']
    __shared__ u16 Vt[64][72];   // [e][l']
    __shared__ u16 St[64][72];   // [e][d]  summed prefix, bf16
    const int tid = threadIdx.x;
    {
        const int row = tid >> 2, q = tid & 3;
        size_t gbase = (size_t)(b*LL + c*64 + row) * DD + h*64 + q*16;
        u16 vv[16];
        #pragma unroll
        for (int i = 0; i < 16; i += 4) {
            *(ushort4*)&Qs[row][q*16 + i] = *(const ushort4*)(Qb + gbase + i);
            *(ushort4*)&Ks[row][q*16 + i] = *(const ushort4*)(Xb + gbase + i);
            *(ushort4*)&vv[i] = *(const ushort4*)(Vb + gbase + i);
        }
        #pragma unroll
        for (int i = 0; i < 16; ++i)
            Vt[q*16 + i][row] = vv[i];
        float facc[16] = {};
        const u16* Sbase = S + ((size_t)(bh * NC) << 12);
        for (int cp = 0; cp < c; ++cp) {
            const u16* Sc = Sbase + ((size_t)cp << 12);
            #pragma unroll
            for (int jj = 0; jj < 4; ++jj) {
                ushort4 sv = *(const ushort4*)(Sc + tid*4 + jj*1024);
                facc[jj*4+0] += bf2f(sv.x);
                facc[jj*4+1] += bf2f(sv.y);
                facc[jj*4+2] += bf2f(sv.z);
                facc[jj*4+3] += bf2f(sv.w);
            }
        }
        #pragma unroll
        for (int jj = 0; jj < 4; ++jj) {
            int g = tid * 4;
            int ij = (g >> 8) & 3, r = (g >> 6) & 3, ln = g & 63;
            int e = (jj & 1)*32 + (ij >> 1)*16 + (ln >> 4)*4 + r;
            int d = (jj >> 1)*32 + (ij & 1)*16 + (ln & 15);
            ushort4 o;
            o.x = f2bf(facc[jj*4+0]);
            o.y = f2bf(facc[jj*4+1]);
            o.z = f2bf(facc[jj*4+2]);
            o.w = f2bf(facc[jj*4+3]);
            *(ushort4*)&St[e][d] = o;
        }
    }
    __syncthreads();
    const int w = tid >> 6, lane = tid & 63, quad = lane >> 4, l16 = lane & 15;
    const int mo = (w & 1) * 32, no = (w >> 1) * 32;

    // P = Q K^T, causal-masked, bf16 (Ps aliases Ks)
    f32x4 pacc[2][2] = {};
    #pragma unroll
    for (int k0 = 0; k0 < 64; k0 += 32) {
        bf16x8 aq[2], bk[2];
        #pragma unroll
        for (int i = 0; i < 2; ++i)
            aq[i] = *(const bf16x8*)&Qs[mo + i*16 + l16][k0 + quad*8];
        #pragma unroll
        for (int j = 0; j < 2; ++j)
            bk[j] = *(const bf16x8*)&Ks[no + j*16 + l16][k0 + quad*8];
        #pragma unroll
        for (int i = 0; i < 2; ++i)
            #pragma unroll
            for (int j = 0; j < 2; ++j)
                pacc[i][j] = __builtin_amdgcn_mfma_f32_16x16x32_bf16(aq[i], bk[j], pacc[i][j], 0, 0, 0);
    }
    __syncthreads();
    #pragma unroll
    for (int i = 0; i < 2; ++i)
        #pragma unroll
        for (int j = 0; j < 2; ++j)
            #pragma unroll
            for (int r = 0; r < 4; ++r) {
                int l  = mo + i*16 + quad*4 + r;
                int lp = no + j*16 + l16;
                Ks[l][lp] = (lp <= l) ? f2bf(pacc[i][j][r]) : (u16)0;
            }
    __syncthreads();

    // O = P @ V + Q @ S0
    f32x4 acc[2][2] = {};
    #pragma unroll
    for (int k0 = 0; k0 < 64; k0 += 32) {
        bf16x8 a1[2], b1[2], a2[2], b2[2];
        #pragma unroll
        for (int i = 0; i < 2; ++i) {
            a1[i] = *(const bf16x8*)&Ks[mo + i*16 + l16][k0 + quad*8];
            a2[i] = *(const bf16x8*)&Qs[mo + i*16 + l16][k0 + quad*8];
        }
        #pragma unroll
        for (int j = 0; j < 2; ++j) {
            b1[j] = *(const bf16x8*)&Vt[no + j*16 + l16][k0 + quad*8];
            b2[j] = *(const bf16x8*)&St[no + j*16 + l16][k0 + quad*8];
        }
        #pragma unroll
        for (int i = 0; i < 2; ++i)
            #pragma unroll
            for (int j = 0; j < 2; ++j) {
                acc[i][j] = __builtin_amdgcn_mfma_f32_16x16x32_bf16(a1[i], b1[j], acc[i][j], 0, 0, 0);
                acc[i][j] = __builtin_amdgcn_mfma_f32_16x16x32_bf16(a2[i], b2[j], acc[i][j], 0, 0, 0);
            }
    }
    float* op = out + (size_t)(b*LL + c*64) * DD + h*64;
    #pragma unroll
    for (int i = 0; i < 2; ++i)
        #pragma unroll
        for (int j = 0; j < 2; ++j)
            #pragma unroll
            for (int r = 0; r < 4; ++r)
                op[(size_t)(mo + i*16 + quad*4 + r) * DD + no + j*16 + l16] = acc[i][j][r];
}

extern "C" void kernel_launch(void* const* d_in, const int* in_sizes, int n_in,
                              void* d_out, int out_size, void* d_ws, size_t ws_size,
                              hipStream_t stream) {
    const float* X  = (const float*)d_in[0];
    const float* Wq = (const float*)d_in[1];
    const float* Wv = (const float*)d_in[2];
    const float* qw = (const float*)d_in[3];
    const float* vw = (const float*)d_in[4];
    float* out = (float*)d_out;

    u16* Xb  = (u16*)d_ws;                        // 2M u16
    u16* Wqb = Xb  + (size_t)2*1024*1024;         // 1M
    u16* Wvb = Wqb + (size_t)1024*1024;           // 1M
    u16* Qb  = Wvb + (size_t)1024*1024;           // 2M
    u16* Vb  = Qb  + (size_t)2*1024*1024;         // 2M
    u16* S   = Vb  + (size_t)2*1024*1024;         // 2M u16

    cvt_k<<<4096, 256, 0, stream>>>(X, Wq, Wv, Xb, Wqb, Wvb);
    gemm_fused<<<dim3(16, 16, 2), 256, 0, stream>>>(Xb, Wqb, Wvb, qw, vw, Qb, Vb, S);
    out_k2<<<BB*HH*NC, 256, 0, stream>>>(Xb, Qb, Vb, S, out);
}